// Round 4
// baseline (2056.158 us; speedup 1.0000x reference)
//
#include <hip/hip_runtime.h>
#include <cstdint>

#define BATCH 128
#define NODES 1023
#define LEAVES 512
#define IN_DIM 300
#define MEM 300
#define NP 320              // padded per-set N (and per-child K)
#define OUT_HALF (BATCH*MEM)

typedef __bf16   bf16x8 __attribute__((ext_vector_type(8)));
typedef short    s16x8  __attribute__((ext_vector_type(8)));
typedef short    s16x4  __attribute__((ext_vector_type(4)));
typedef float    f32x4  __attribute__((ext_vector_type(4)));
typedef _Float16 half_t;

__device__ __forceinline__ short f2bf(float f) {
    unsigned u = __float_as_uint(f);
    u += 0x7fff + ((u >> 16) & 1);
    return (short)(u >> 16);
}
__device__ __forceinline__ float sigf(float x)  { return 1.0f / (1.0f + __expf(-x)); }
__device__ __forceinline__ float tanhf_(float x){ return 1.0f - 2.0f / (1.0f + __expf(2.0f * x)); }

__device__ __forceinline__ f32x4 mfma16(s16x8 a, s16x8 b, f32x4 c) {
    return __builtin_amdgcn_mfma_f32_16x16x32_bf16(
        __builtin_bit_cast(bf16x8, a), __builtin_bit_cast(bf16x8, b), c, 0, 0, 0);
}

// ---------- weight packing: B-fragment order ----------
// frag-block (kb,s,nb): 64 lanes x 8 bf16; lane l holds B[k=kb*32+(l>>4)*8+j][n=nb*16+(l&15)]
__global__ __launch_bounds__(256) void pack_node_w(
    const float* __restrict__ Wiouh, const float* __restrict__ Wfh, short* __restrict__ Wpk)
{
    int gid = blockIdx.x * 256 + threadIdx.x;           // 2000 frags * 64 lanes
    if (gid >= 2000 * 64) return;
    int fb = gid >> 6, l = gid & 63;
    int kb = fb / 100, rem = fb % 100, s = rem / 20, nb = rem % 20;
    int n = nb * 16 + (l & 15);
    int kbase = kb * 32 + (l >> 4) * 8;                 // k' in [0,640)
    short v[8];
#pragma unroll
    for (int j = 0; j < 8; ++j) {
        int kp = kbase + j;
        int side = kp >= NP;
        int kk = kp - side * NP;
        float f = 0.0f;
        if (kk < MEM && n < MEM) {
            int k = side * MEM + kk;
            f = (s < 3) ? Wiouh[(size_t)k * 900 + s * 300 + n]
                        : Wfh[(size_t)k * 600 + (s - 3) * 300 + n];
        }
        v[j] = f2bf(f);
    }
    *(s16x8*)&Wpk[(size_t)gid * 8] = *(s16x8*)v;
}

__global__ __launch_bounds__(256) void pack_leaf_w(
    const float* __restrict__ Wfioux, short* __restrict__ Wpk)
{
    int gid = blockIdx.x * 256 + threadIdx.x;           // 600 frags * 64 lanes
    if (gid >= 600 * 64) return;
    int fb = gid >> 6, l = gid & 63;
    int kb = fb / 60, rem = fb % 60, s = rem / 20, nb = rem % 20;
    int n = nb * 16 + (l & 15);
    int kbase = kb * 32 + (l >> 4) * 8;                 // k' in [0,320)
    short v[8];
#pragma unroll
    for (int j = 0; j < 8; ++j) {
        int kp = kbase + j;
        float f = 0.0f;
        if (kp < IN_DIM && n < MEM)
            f = Wfioux[(size_t)kp * 1200 + (s + 1) * 300 + n];
        v[j] = f2bf(f);
    }
    *(s16x8*)&Wpk[(size_t)gid * 8] = *(s16x8*)v;
}

// ---------- leaf-input packing: X[leaf][b][kp] bf16, kp padded to 320 ----------
__global__ __launch_bounds__(256) void pack_x(
    const float* __restrict__ inputs, short* __restrict__ X)
{
    int gid = blockIdx.x * 256 + threadIdx.x;           // 512*128*80 quads
    if (gid >= LEAVES * BATCH * (NP / 4)) return;
    int q = gid % (NP / 4);
    int rb = gid / (NP / 4);
    int b = rb % BATCH, leaf = rb / BATCH;
    short v[4] = {0, 0, 0, 0};
    if (q < IN_DIM / 4) {
        f32x4 f = *(const f32x4*)&inputs[((size_t)b * NODES + leaf) * IN_DIM + q * 4];
        v[0] = f2bf(f[0]); v[1] = f2bf(f[1]); v[2] = f2bf(f[2]); v[3] = f2bf(f[3]);
    }
    *(s16x4*)&X[(size_t)gid * 4] = *(s16x4*)v;
}

// ---------- leaf GEMM+gates: 32-col slices, no LDS, no barriers ----------
// waves: wm in {0,1} (64 rows), wn in {0,1} (16 cols); acc = 3 sets x 4 mi = 48 f32
__global__ __launch_bounds__(256, 6) void leaf_mfma(
    const short* __restrict__ X, const short* __restrict__ Wpk,
    const float* __restrict__ b_fioux, half_t* __restrict__ C, short* __restrict__ H)
{
    const int t = threadIdx.x;
    const int l = t & 63, w = t >> 6;
    const int wm = w >> 1, wn = w & 1;
    const int lane16 = l & 15, quad = l >> 4;
    const int leaf = blockIdx.x;
    const int nf = blockIdx.y * 2 + wn;                 // 16-col fragment index

    const short* Xb = X + (size_t)leaf * BATCH * NP;

    f32x4 acc[3][4];
#pragma unroll
    for (int s = 0; s < 3; ++s)
#pragma unroll
        for (int mi = 0; mi < 4; ++mi) acc[s][mi] = (f32x4)(0.0f);

    for (int kb = 0; kb < 10; ++kb) {
        const int koff = kb * 32 + quad * 8;
        s16x8 a[4];
#pragma unroll
        for (int mi = 0; mi < 4; ++mi)
            a[mi] = *(const s16x8*)(Xb + (size_t)(wm * 64 + mi * 16 + lane16) * NP + koff);
#pragma unroll
        for (int s = 0; s < 3; ++s) {
            s16x8 bfr = *(const s16x8*)&Wpk[((size_t)((kb * 3 + s) * 20 + nf) * 64 + l) * 8];
#pragma unroll
            for (int mi = 0; mi < 4; ++mi)
                acc[s][mi] = mfma16(a[mi], bfr, acc[s][mi]);
        }
    }

    const int col = nf * 16 + lane16;
    const bool valid = col < MEM;
    float bi = 0, bo = 0, bu = 0;
    if (valid) { bi = b_fioux[300 + col]; bo = b_fioux[600 + col]; bu = b_fioux[900 + col]; }
#pragma unroll
    for (int mi = 0; mi < 4; ++mi)
#pragma unroll
        for (int r = 0; r < 4; ++r) {
            int b = wm * 64 + mi * 16 + quad * 4 + r;
            size_t hIdx = ((size_t)leaf * BATCH + b) * NP + col;
            if (valid) {
                float ig = sigf(acc[0][mi][r] + bi);
                float og = sigf(acc[1][mi][r] + bo);
                float ug = tanhf_(acc[2][mi][r] + bu);
                float c = ig * ug;
                float h = og * tanhf_(c);
                C[((size_t)leaf * BATCH + b) * MEM + col] = (half_t)c;
                H[hIdx] = f2bf(h);
            } else {
                H[hIdx] = 0;
            }
        }
}

// ---------- internal node GEMM+gates: 32-col slices, no LDS, no barriers ----------
// waves: wm in {0,1} (64 rows), wn in {0,1} (16 cols); acc = 5 sets x 4 mi = 80 f32
__global__ __launch_bounds__(256, 6) void node_mfma(
    const short* __restrict__ Wpk, const float* __restrict__ b_fioux,
    const int* __restrict__ left_idx, const int* __restrict__ right_idx,
    half_t* __restrict__ C, short* __restrict__ H,
    int level_start, float* __restrict__ out)
{
    const int t = threadIdx.x;
    const int l = t & 63, w = t >> 6;
    const int wm = w >> 1, wn = w & 1;
    const int lane16 = l & 15, quad = l >> 4;
    const int node = level_start + blockIdx.x;
    const int nf = blockIdx.y * 2 + wn;                 // 16-col fragment index

    const int li = left_idx[node], ri = right_idx[node];
    const short* HL = H + (size_t)li * BATCH * NP;
    const short* HR = H + (size_t)ri * BATCH * NP;

    f32x4 acc[5][4];
#pragma unroll
    for (int s = 0; s < 5; ++s)
#pragma unroll
        for (int mi = 0; mi < 4; ++mi) acc[s][mi] = (f32x4)(0.0f);

    for (int kb = 0; kb < 20; ++kb) {
        const int side = kb >= 10;
        const int koff = (kb - side * 10) * 32 + quad * 8;
        const short* Hb = (side ? HR : HL) + koff;
        s16x8 a[4];
#pragma unroll
        for (int mi = 0; mi < 4; ++mi)
            a[mi] = *(const s16x8*)(Hb + (size_t)(wm * 64 + mi * 16 + lane16) * NP);
#pragma unroll
        for (int s = 0; s < 5; ++s) {
            s16x8 bfr = *(const s16x8*)&Wpk[((size_t)((kb * 5 + s) * 20 + nf) * 64 + l) * 8];
#pragma unroll
            for (int mi = 0; mi < 4; ++mi)
                acc[s][mi] = mfma16(a[mi], bfr, acc[s][mi]);
        }
    }

    const int col = nf * 16 + lane16;
    const bool valid = col < MEM;
    float bff = 0, bi = 0, bo = 0, bu = 0;
    if (valid) {
        bff = b_fioux[col]; bi = b_fioux[300 + col];
        bo = b_fioux[600 + col]; bu = b_fioux[900 + col];
    }
#pragma unroll
    for (int mi = 0; mi < 4; ++mi)
#pragma unroll
        for (int r = 0; r < 4; ++r) {
            int row = wm * 64 + mi * 16 + quad * 4 + r;
            size_t hIdx = ((size_t)node * BATCH + row) * NP + col;
            if (valid) {
                float cl = (float)C[((size_t)li * BATCH + row) * MEM + col];
                float cr = (float)C[((size_t)ri * BATCH + row) * MEM + col];
                float ig = sigf(acc[0][mi][r] + bi);
                float og = sigf(acc[1][mi][r] + bo);
                float ug = tanhf_(acc[2][mi][r] + bu);
                float fl = sigf(acc[3][mi][r] + bff);
                float fr = sigf(acc[4][mi][r] + bff);
                float c = ig * ug + fl * cl + fr * cr;
                float h = og * tanhf_(c);
                C[((size_t)node * BATCH + row) * MEM + col] = (half_t)c;
                H[hIdx] = f2bf(h);
                if (out) {
                    out[row * MEM + col] = c;
                    out[OUT_HALF + row * MEM + col] = h;
                }
            } else {
                H[hIdx] = 0;
            }
        }
}

extern "C" void kernel_launch(void* const* d_in, const int* in_sizes, int n_in,
                              void* d_out, int out_size, void* d_ws, size_t ws_size,
                              hipStream_t stream) {
    const float* inputs  = (const float*)d_in[0];
    const float* Wfioux  = (const float*)d_in[1];
    const float* b_fioux = (const float*)d_in[2];
    const float* Wiouh   = (const float*)d_in[3];
    const float* Wfh     = (const float*)d_in[4];
    const int*   left_idx  = (const int*)d_in[5];
    const int*   right_idx = (const int*)d_in[6];

    half_t* C   = (half_t*)d_ws;                              // [1023][128][300] fp16
    short*  H   = (short*)(C + (size_t)NODES * BATCH * MEM);  // [1023][128][320] bf16
    short* WpkN = H + (size_t)NODES * BATCH * NP;             // 2000 frag-blocks
    short* WpkL = WpkN + (size_t)2000 * 512;                  // 600 frag-blocks
    short* X    = WpkL + (size_t)600 * 512;                   // [512][128][320] bf16
    float* out  = (float*)d_out;

    pack_x<<<(LEAVES * BATCH * (NP / 4) + 255) / 256, 256, 0, stream>>>(inputs, X);
    pack_leaf_w<<<150, 256, 0, stream>>>(Wfioux, WpkL);
    pack_node_w<<<500, 256, 0, stream>>>(Wiouh, Wfh, WpkN);

    leaf_mfma<<<dim3(LEAVES, 10), 256, 0, stream>>>(X, WpkL, b_fioux, C, H);

    static const int starts[9] = {512, 768, 896, 960, 992, 1008, 1016, 1020, 1022};
    static const int sizes [9] = {256, 128,  64,  32,  16,    8,    4,    2,    1};
    for (int lvl = 0; lvl < 9; ++lvl) {
        bool root = (lvl == 8);
        node_mfma<<<dim3(sizes[lvl], 10), 256, 0, stream>>>(
            WpkN, b_fioux, left_idx, right_idx, C, H, starts[lvl],
            root ? out : nullptr);
    }
}

// Round 5
// 807.511 us; speedup vs baseline: 2.5463x; 2.5463x over previous
//
#include <hip/hip_runtime.h>
#include <cstdint>

#define BATCH 128
#define NODES 1023
#define LEAVES 512
#define IN_DIM 300
#define MEM 300
#define NP 320              // padded per-set N (and per-child K)
#define OUT_HALF (BATCH*MEM)

typedef __bf16   bf16x8 __attribute__((ext_vector_type(8)));
typedef short    s16x8  __attribute__((ext_vector_type(8)));
typedef short    s16x4  __attribute__((ext_vector_type(4)));
typedef float    f32x4  __attribute__((ext_vector_type(4)));
typedef _Float16 half_t;

__device__ __forceinline__ short f2bf(float f) {
    unsigned u = __float_as_uint(f);
    u += 0x7fff + ((u >> 16) & 1);
    return (short)(u >> 16);
}
__device__ __forceinline__ float sigf(float x)  { return 1.0f / (1.0f + __expf(-x)); }
__device__ __forceinline__ float tanhf_(float x){ return 1.0f - 2.0f / (1.0f + __expf(2.0f * x)); }

__device__ __forceinline__ f32x4 mfma16(s16x8 a, s16x8 b, f32x4 c) {
    return __builtin_amdgcn_mfma_f32_16x16x32_bf16(
        __builtin_bit_cast(bf16x8, a), __builtin_bit_cast(bf16x8, b), c, 0, 0, 0);
}

// ---------- weight packing: B-fragment order ----------
// frag-block (kb,s,nb): 64 lanes x 8 bf16; lane l holds B[k=kb*32+(l>>4)*8+j][n=nb*16+(l&15)]
__global__ __launch_bounds__(256) void pack_node_w(
    const float* __restrict__ Wiouh, const float* __restrict__ Wfh, short* __restrict__ Wpk)
{
    int gid = blockIdx.x * 256 + threadIdx.x;           // 2000 frags * 64 lanes
    if (gid >= 2000 * 64) return;
    int fb = gid >> 6, l = gid & 63;
    int kb = fb / 100, rem = fb % 100, s = rem / 20, nb = rem % 20;
    int n = nb * 16 + (l & 15);
    int kbase = kb * 32 + (l >> 4) * 8;                 // k' in [0,640)
    short v[8];
#pragma unroll
    for (int j = 0; j < 8; ++j) {
        int kp = kbase + j;
        int side = kp >= NP;
        int kk = kp - side * NP;
        float f = 0.0f;
        if (kk < MEM && n < MEM) {
            int k = side * MEM + kk;
            f = (s < 3) ? Wiouh[(size_t)k * 900 + s * 300 + n]
                        : Wfh[(size_t)k * 600 + (s - 3) * 300 + n];
        }
        v[j] = f2bf(f);
    }
    *(s16x8*)&Wpk[(size_t)gid * 8] = *(s16x8*)v;
}

__global__ __launch_bounds__(256) void pack_leaf_w(
    const float* __restrict__ Wfioux, short* __restrict__ Wpk)
{
    int gid = blockIdx.x * 256 + threadIdx.x;           // 600 frags * 64 lanes
    if (gid >= 600 * 64) return;
    int fb = gid >> 6, l = gid & 63;
    int kb = fb / 60, rem = fb % 60, s = rem / 20, nb = rem % 20;
    int n = nb * 16 + (l & 15);
    int kbase = kb * 32 + (l >> 4) * 8;                 // k' in [0,320)
    short v[8];
#pragma unroll
    for (int j = 0; j < 8; ++j) {
        int kp = kbase + j;
        float f = 0.0f;
        if (kp < IN_DIM && n < MEM)
            f = Wfioux[(size_t)kp * 1200 + (s + 1) * 300 + n];
        v[j] = f2bf(f);
    }
    *(s16x8*)&Wpk[(size_t)gid * 8] = *(s16x8*)v;
}

// ---------- leaf-input packing: X[leaf][b][kp] bf16, kp padded to 320 ----------
__global__ __launch_bounds__(256) void pack_x(
    const float* __restrict__ inputs, short* __restrict__ X)
{
    int gid = blockIdx.x * 256 + threadIdx.x;           // 512*128*80 quads
    if (gid >= LEAVES * BATCH * (NP / 4)) return;
    int q = gid % (NP / 4);
    int rb = gid / (NP / 4);
    int b = rb % BATCH, leaf = rb / BATCH;
    short v[4] = {0, 0, 0, 0};
    if (q < IN_DIM / 4) {
        f32x4 f = *(const f32x4*)&inputs[((size_t)b * NODES + leaf) * IN_DIM + q * 4];
        v[0] = f2bf(f[0]); v[1] = f2bf(f[1]); v[2] = f2bf(f[2]); v[3] = f2bf(f[3]);
    }
    *(s16x4*)&X[(size_t)gid * 4] = *(s16x4*)v;
}

// ---------- leaf GEMM+gates: wave = 32 rows x 16 cols, no LDS, no barriers ----------
// acc = 3 sets x 2 mi = 24 f32; launch_bounds(256,4) -> 128-reg budget, no spill
__global__ __launch_bounds__(256, 4) void leaf_mfma(
    const short* __restrict__ X, const short* __restrict__ Wpk,
    const float* __restrict__ b_fioux, half_t* __restrict__ C, short* __restrict__ H)
{
    const int t = threadIdx.x;
    const int l = t & 63, w = t >> 6;       // w = row-group 0..3
    const int lane16 = l & 15, quad = l >> 4;
    const int leaf = blockIdx.x;
    const int nf = blockIdx.y;              // 16-col fragment index 0..19

    const short* Xb = X + (size_t)leaf * BATCH * NP;

    f32x4 acc[3][2];
#pragma unroll
    for (int s = 0; s < 3; ++s)
#pragma unroll
        for (int mi = 0; mi < 2; ++mi) acc[s][mi] = (f32x4)(0.0f);

    for (int kb = 0; kb < 10; ++kb) {
        const int koff = kb * 32 + quad * 8;
        s16x8 a[2];
#pragma unroll
        for (int mi = 0; mi < 2; ++mi)
            a[mi] = *(const s16x8*)(Xb + (size_t)(w * 32 + mi * 16 + lane16) * NP + koff);
#pragma unroll
        for (int s = 0; s < 3; ++s) {
            s16x8 bfr = *(const s16x8*)&Wpk[((size_t)((kb * 3 + s) * 20 + nf) * 64 + l) * 8];
#pragma unroll
            for (int mi = 0; mi < 2; ++mi)
                acc[s][mi] = mfma16(a[mi], bfr, acc[s][mi]);
        }
    }

    const int col = nf * 16 + lane16;
    const bool valid = col < MEM;
    float bi = 0, bo = 0, bu = 0;
    if (valid) { bi = b_fioux[300 + col]; bo = b_fioux[600 + col]; bu = b_fioux[900 + col]; }
#pragma unroll
    for (int mi = 0; mi < 2; ++mi)
#pragma unroll
        for (int r = 0; r < 4; ++r) {
            int b = w * 32 + mi * 16 + quad * 4 + r;
            size_t hIdx = ((size_t)leaf * BATCH + b) * NP + col;
            if (valid) {
                float ig = sigf(acc[0][mi][r] + bi);
                float og = sigf(acc[1][mi][r] + bo);
                float ug = tanhf_(acc[2][mi][r] + bu);
                float c = ig * ug;
                float h = og * tanhf_(c);
                C[((size_t)leaf * BATCH + b) * MEM + col] = (half_t)c;
                H[hIdx] = f2bf(h);
            } else {
                H[hIdx] = 0;
            }
        }
}

// ---------- internal node GEMM+gates: wave = 32 rows x 16 cols ----------
// acc = 5 sets x 2 mi = 40 f32; launch_bounds(256,4) -> 128-reg budget
__global__ __launch_bounds__(256, 4) void node_mfma(
    const short* __restrict__ Wpk, const float* __restrict__ b_fioux,
    const int* __restrict__ left_idx, const int* __restrict__ right_idx,
    half_t* __restrict__ C, short* __restrict__ H,
    int level_start, float* __restrict__ out)
{
    const int t = threadIdx.x;
    const int l = t & 63, w = t >> 6;       // w = row-group 0..3
    const int lane16 = l & 15, quad = l >> 4;
    const int node = level_start + blockIdx.x;
    const int nf = blockIdx.y;              // 16-col fragment index 0..19

    const int li = left_idx[node], ri = right_idx[node];
    const short* HL = H + (size_t)li * BATCH * NP;
    const short* HR = H + (size_t)ri * BATCH * NP;

    f32x4 acc[5][2];
#pragma unroll
    for (int s = 0; s < 5; ++s)
#pragma unroll
        for (int mi = 0; mi < 2; ++mi) acc[s][mi] = (f32x4)(0.0f);

    for (int kb = 0; kb < 20; ++kb) {
        const int side = kb >= 10;
        const int koff = (kb - side * 10) * 32 + quad * 8;
        const short* Hb = (side ? HR : HL) + koff;
        s16x8 a[2];
#pragma unroll
        for (int mi = 0; mi < 2; ++mi)
            a[mi] = *(const s16x8*)(Hb + (size_t)(w * 32 + mi * 16 + lane16) * NP);
#pragma unroll
        for (int s = 0; s < 5; ++s) {
            s16x8 bfr = *(const s16x8*)&Wpk[((size_t)((kb * 5 + s) * 20 + nf) * 64 + l) * 8];
#pragma unroll
            for (int mi = 0; mi < 2; ++mi)
                acc[s][mi] = mfma16(a[mi], bfr, acc[s][mi]);
        }
    }

    const int col = nf * 16 + lane16;
    const bool valid = col < MEM;
    float bff = 0, bi = 0, bo = 0, bu = 0;
    if (valid) {
        bff = b_fioux[col]; bi = b_fioux[300 + col];
        bo = b_fioux[600 + col]; bu = b_fioux[900 + col];
    }
#pragma unroll
    for (int mi = 0; mi < 2; ++mi)
#pragma unroll
        for (int r = 0; r < 4; ++r) {
            int row = w * 32 + mi * 16 + quad * 4 + r;
            size_t hIdx = ((size_t)node * BATCH + row) * NP + col;
            if (valid) {
                float cl = (float)C[((size_t)li * BATCH + row) * MEM + col];
                float cr = (float)C[((size_t)ri * BATCH + row) * MEM + col];
                float ig = sigf(acc[0][mi][r] + bi);
                float og = sigf(acc[1][mi][r] + bo);
                float ug = tanhf_(acc[2][mi][r] + bu);
                float fl = sigf(acc[3][mi][r] + bff);
                float fr = sigf(acc[4][mi][r] + bff);
                float c = ig * ug + fl * cl + fr * cr;
                float h = og * tanhf_(c);
                C[((size_t)node * BATCH + row) * MEM + col] = (half_t)c;
                H[hIdx] = f2bf(h);
                if (out) {
                    out[row * MEM + col] = c;
                    out[OUT_HALF + row * MEM + col] = h;
                }
            } else {
                H[hIdx] = 0;
            }
        }
}

extern "C" void kernel_launch(void* const* d_in, const int* in_sizes, int n_in,
                              void* d_out, int out_size, void* d_ws, size_t ws_size,
                              hipStream_t stream) {
    const float* inputs  = (const float*)d_in[0];
    const float* Wfioux  = (const float*)d_in[1];
    const float* b_fioux = (const float*)d_in[2];
    const float* Wiouh   = (const float*)d_in[3];
    const float* Wfh     = (const float*)d_in[4];
    const int*   left_idx  = (const int*)d_in[5];
    const int*   right_idx = (const int*)d_in[6];

    half_t* C   = (half_t*)d_ws;                              // [1023][128][300] fp16
    short*  H   = (short*)(C + (size_t)NODES * BATCH * MEM);  // [1023][128][320] bf16
    short* WpkN = H + (size_t)NODES * BATCH * NP;             // 2000 frag-blocks
    short* WpkL = WpkN + (size_t)2000 * 512;                  // 600 frag-blocks
    short* X    = WpkL + (size_t)600 * 512;                   // [512][128][320] bf16
    float* out  = (float*)d_out;

    pack_x<<<(LEAVES * BATCH * (NP / 4) + 255) / 256, 256, 0, stream>>>(inputs, X);
    pack_leaf_w<<<150, 256, 0, stream>>>(Wfioux, WpkL);
    pack_node_w<<<500, 256, 0, stream>>>(Wiouh, Wfh, WpkN);

    leaf_mfma<<<dim3(LEAVES, 20), 256, 0, stream>>>(X, WpkL, b_fioux, C, H);

    static const int starts[9] = {512, 768, 896, 960, 992, 1008, 1016, 1020, 1022};
    static const int sizes [9] = {256, 128,  64,  32,  16,    8,    4,    2,    1};
    for (int lvl = 0; lvl < 9; ++lvl) {
        bool root = (lvl == 8);
        node_mfma<<<dim3(sizes[lvl], 20), 256, 0, stream>>>(
            WpkN, b_fioux, left_idx, right_idx, C, H, starts[lvl],
            root ? out : nullptr);
    }
}

// Round 6
// 698.282 us; speedup vs baseline: 2.9446x; 1.1564x over previous
//
#include <hip/hip_runtime.h>
#include <cstdint>

#define BATCH 128
#define NODES 1023
#define LEAVES 512
#define IN_DIM 300
#define MEM 300
#define NP 320              // padded per-set N (and per-child K)
#define OUT_HALF (BATCH*MEM)

typedef __bf16   bf16x8 __attribute__((ext_vector_type(8)));
typedef short    s16x8  __attribute__((ext_vector_type(8)));
typedef short    s16x4  __attribute__((ext_vector_type(4)));
typedef float    f32x4  __attribute__((ext_vector_type(4)));
typedef _Float16 half_t;

__device__ __forceinline__ short f2bf(float f) {
    unsigned u = __float_as_uint(f);
    u += 0x7fff + ((u >> 16) & 1);
    return (short)(u >> 16);
}
__device__ __forceinline__ float sigf(float x)  { return 1.0f / (1.0f + __expf(-x)); }
__device__ __forceinline__ float tanhf_(float x){ return 1.0f - 2.0f / (1.0f + __expf(2.0f * x)); }

__device__ __forceinline__ f32x4 mfma16(s16x8 a, s16x8 b, f32x4 c) {
    return __builtin_amdgcn_mfma_f32_16x16x32_bf16(
        __builtin_bit_cast(bf16x8, a), __builtin_bit_cast(bf16x8, b), c, 0, 0, 0);
}

// async 16B/lane global->LDS: lds dst = wave-uniform base + lane*16
__device__ __forceinline__ void dma16(const short* src, short* ldsBase) {
    __builtin_amdgcn_global_load_lds(
        (const __attribute__((address_space(1))) unsigned int*)src,
        (__attribute__((address_space(3))) unsigned int*)ldsBase,
        16, 0, 0);
}

// ---------- weight packing: B-fragment order ----------
// frag-block (kb,s,nb): 64 lanes x 8 bf16; lane l holds B[k=kb*32+(l>>4)*8+j][n=nb*16+(l&15)]
__global__ __launch_bounds__(256) void pack_node_w(
    const float* __restrict__ Wiouh, const float* __restrict__ Wfh, short* __restrict__ Wpk)
{
    int gid = blockIdx.x * 256 + threadIdx.x;           // 2000 frags * 64 lanes
    if (gid >= 2000 * 64) return;
    int fb = gid >> 6, l = gid & 63;
    int kb = fb / 100, rem = fb % 100, s = rem / 20, nb = rem % 20;
    int n = nb * 16 + (l & 15);
    int kbase = kb * 32 + (l >> 4) * 8;                 // k' in [0,640)
    short v[8];
#pragma unroll
    for (int j = 0; j < 8; ++j) {
        int kp = kbase + j;
        int side = kp >= NP;
        int kk = kp - side * NP;
        float f = 0.0f;
        if (kk < MEM && n < MEM) {
            int k = side * MEM + kk;
            f = (s < 3) ? Wiouh[(size_t)k * 900 + s * 300 + n]
                        : Wfh[(size_t)k * 600 + (s - 3) * 300 + n];
        }
        v[j] = f2bf(f);
    }
    *(s16x8*)&Wpk[(size_t)gid * 8] = *(s16x8*)v;
}

__global__ __launch_bounds__(256) void pack_leaf_w(
    const float* __restrict__ Wfioux, short* __restrict__ Wpk)
{
    int gid = blockIdx.x * 256 + threadIdx.x;           // 600 frags * 64 lanes
    if (gid >= 600 * 64) return;
    int fb = gid >> 6, l = gid & 63;
    int kb = fb / 60, rem = fb % 60, s = rem / 20, nb = rem % 20;
    int n = nb * 16 + (l & 15);
    int kbase = kb * 32 + (l >> 4) * 8;                 // k' in [0,320)
    short v[8];
#pragma unroll
    for (int j = 0; j < 8; ++j) {
        int kp = kbase + j;
        float f = 0.0f;
        if (kp < IN_DIM && n < MEM)
            f = Wfioux[(size_t)kp * 1200 + (s + 1) * 300 + n];
        v[j] = f2bf(f);
    }
    *(s16x8*)&Wpk[(size_t)gid * 8] = *(s16x8*)v;
}

// ---------- leaf-input packing: X[leaf][b][kp] bf16, kp padded to 320 ----------
__global__ __launch_bounds__(256) void pack_x(
    const float* __restrict__ inputs, short* __restrict__ X)
{
    int gid = blockIdx.x * 256 + threadIdx.x;           // 512*128*80 quads
    if (gid >= LEAVES * BATCH * (NP / 4)) return;
    int q = gid % (NP / 4);
    int rb = gid / (NP / 4);
    int b = rb % BATCH, leaf = rb / BATCH;
    short v[4] = {0, 0, 0, 0};
    if (q < IN_DIM / 4) {
        f32x4 f = *(const f32x4*)&inputs[((size_t)b * NODES + leaf) * IN_DIM + q * 4];
        v[0] = f2bf(f[0]); v[1] = f2bf(f[1]); v[2] = f2bf(f[2]); v[3] = f2bf(f[3]);
    }
    *(s16x4*)&X[(size_t)gid * 4] = *(s16x4*)v;
}

// ---------- leaf GEMM+gates: block = 1 leaf x 64-col group, B staged in LDS ----------
// wave = 32 rows x (3 sets x 4 frags); acc = 24 f32x4 = 96 f32
__global__ __launch_bounds__(256, 3) void leaf_mfma(
    const short* __restrict__ X, const short* __restrict__ Wpk,
    const float* __restrict__ b_fioux, half_t* __restrict__ C, short* __restrict__ H)
{
    __shared__ short Bs[12 * 512];                      // 12 frags x 1KB
    const int t = threadIdx.x;
    const int l = t & 63, w = t >> 6;                   // 4 waves, w = row-group
    const int lane16 = l & 15, quad = l >> 4;
    const int leaf = blockIdx.x;
    const int y = blockIdx.y;                           // 64-col group 0..4

    const short* Xb = X + (size_t)leaf * BATCH * NP;

    f32x4 acc[3][4][2];                                 // [set][frag][row-half]
#pragma unroll
    for (int s = 0; s < 3; ++s)
#pragma unroll
        for (int f = 0; f < 4; ++f)
#pragma unroll
            for (int mi = 0; mi < 2; ++mi) acc[s][f][mi] = (f32x4)(0.0f);

    for (int kb = 0; kb < 10; ++kb) {
        const int koff = kb * 32 + quad * 8;
        // DMA 12 B-frags into LDS (3 per wave)
#pragma unroll
        for (int fl = w; fl < 12; fl += 4) {
            int s = fl >> 2, f = fl & 3;
            const short* src = Wpk + ((size_t)((kb * 3 + s) * 20 + y * 4 + f) * 64 + l) * 8;
            dma16(src, &Bs[fl * 512]);
        }
        s16x8 a[2];
        a[0] = *(const s16x8*)(Xb + (size_t)(w * 32 + lane16) * NP + koff);
        a[1] = *(const s16x8*)(Xb + (size_t)(w * 32 + 16 + lane16) * NP + koff);
        __syncthreads();
#pragma unroll
        for (int s = 0; s < 3; ++s)
#pragma unroll
            for (int f = 0; f < 4; ++f) {
                s16x8 b = *(const s16x8*)&Bs[(s * 4 + f) * 512 + l * 8];
                acc[s][f][0] = mfma16(a[0], b, acc[s][f][0]);
                acc[s][f][1] = mfma16(a[1], b, acc[s][f][1]);
            }
        __syncthreads();
    }

#pragma unroll
    for (int f = 0; f < 4; ++f) {
        const int col = y * 64 + f * 16 + lane16;
        const bool valid = col < MEM;
        float bi = 0, bo = 0, bu = 0;
        if (valid) { bi = b_fioux[300 + col]; bo = b_fioux[600 + col]; bu = b_fioux[900 + col]; }
#pragma unroll
        for (int mi = 0; mi < 2; ++mi)
#pragma unroll
            for (int r = 0; r < 4; ++r) {
                int b = w * 32 + mi * 16 + quad * 4 + r;
                size_t hIdx = ((size_t)leaf * BATCH + b) * NP + col;
                if (valid) {
                    float ig = sigf(acc[0][f][mi][r] + bi);
                    float og = sigf(acc[1][f][mi][r] + bo);
                    float ug = tanhf_(acc[2][f][mi][r] + bu);
                    float c = ig * ug;
                    float h = og * tanhf_(c);
                    C[((size_t)leaf * BATCH + b) * MEM + col] = (half_t)c;
                    H[hIdx] = f2bf(h);
                } else {
                    H[hIdx] = 0;
                }
            }
    }
}

// ---------- internal node GEMM+gates: block = 1 node x 32-col group, B in LDS ----------
// wave = 32 rows x (5 sets x 2 frags); acc = 20 f32x4 = 80 f32
__global__ __launch_bounds__(256, 3) void node_mfma(
    const short* __restrict__ Wpk, const float* __restrict__ b_fioux,
    const int* __restrict__ left_idx, const int* __restrict__ right_idx,
    half_t* __restrict__ C, short* __restrict__ H,
    int level_start, float* __restrict__ out)
{
    __shared__ short Bs[10 * 512];                      // 10 frags x 1KB
    const int t = threadIdx.x;
    const int l = t & 63, w = t >> 6;                   // 4 waves, w = row-group
    const int lane16 = l & 15, quad = l >> 4;
    const int node = level_start + blockIdx.x;
    const int y = blockIdx.y;                           // 32-col group 0..9

    const int li = left_idx[node], ri = right_idx[node];
    const short* HL = H + (size_t)li * BATCH * NP;
    const short* HR = H + (size_t)ri * BATCH * NP;

    f32x4 acc[5][2][2];                                 // [set][frag][row-half]
#pragma unroll
    for (int s = 0; s < 5; ++s)
#pragma unroll
        for (int f = 0; f < 2; ++f)
#pragma unroll
            for (int mi = 0; mi < 2; ++mi) acc[s][f][mi] = (f32x4)(0.0f);

    for (int kb = 0; kb < 20; ++kb) {
        const int side = kb >= 10;
        const int koff = (kb - side * 10) * 32 + quad * 8;
        const short* Hb = (side ? HR : HL) + koff;
        // DMA 10 B-frags into LDS
#pragma unroll
        for (int fl = w; fl < 10; fl += 4) {
            int s = fl >> 1, f = fl & 1;
            const short* src = Wpk + ((size_t)((kb * 5 + s) * 20 + y * 2 + f) * 64 + l) * 8;
            dma16(src, &Bs[fl * 512]);
        }
        s16x8 a[2];
        a[0] = *(const s16x8*)(Hb + (size_t)(w * 32 + lane16) * NP);
        a[1] = *(const s16x8*)(Hb + (size_t)(w * 32 + 16 + lane16) * NP);
        __syncthreads();
#pragma unroll
        for (int s = 0; s < 5; ++s)
#pragma unroll
            for (int f = 0; f < 2; ++f) {
                s16x8 b = *(const s16x8*)&Bs[(s * 2 + f) * 512 + l * 8];
                acc[s][f][0] = mfma16(a[0], b, acc[s][f][0]);
                acc[s][f][1] = mfma16(a[1], b, acc[s][f][1]);
            }
        __syncthreads();
    }

#pragma unroll
    for (int f = 0; f < 2; ++f) {
        const int col = y * 32 + f * 16 + lane16;
        const bool valid = col < MEM;
        float bff = 0, bi = 0, bo = 0, bu = 0;
        if (valid) {
            bff = b_fioux[col]; bi = b_fioux[300 + col];
            bo = b_fioux[600 + col]; bu = b_fioux[900 + col];
        }
#pragma unroll
        for (int mi = 0; mi < 2; ++mi)
#pragma unroll
            for (int r = 0; r < 4; ++r) {
                int row = w * 32 + mi * 16 + quad * 4 + r;
                size_t hIdx = ((size_t)node * BATCH + row) * NP + col;
                if (valid) {
                    float cl = (float)C[((size_t)li * BATCH + row) * MEM + col];
                    float cr = (float)C[((size_t)ri * BATCH + row) * MEM + col];
                    float ig = sigf(acc[0][f][mi][r] + bi);
                    float og = sigf(acc[1][f][mi][r] + bo);
                    float ug = tanhf_(acc[2][f][mi][r] + bu);
                    float fl = sigf(acc[3][f][mi][r] + bff);
                    float fr = sigf(acc[4][f][mi][r] + bff);
                    float c = ig * ug + fl * cl + fr * cr;
                    float h = og * tanhf_(c);
                    C[((size_t)node * BATCH + row) * MEM + col] = (half_t)c;
                    H[hIdx] = f2bf(h);
                    if (out) {
                        out[row * MEM + col] = c;
                        out[OUT_HALF + row * MEM + col] = h;
                    }
                } else {
                    H[hIdx] = 0;
                }
            }
    }
}

extern "C" void kernel_launch(void* const* d_in, const int* in_sizes, int n_in,
                              void* d_out, int out_size, void* d_ws, size_t ws_size,
                              hipStream_t stream) {
    const float* inputs  = (const float*)d_in[0];
    const float* Wfioux  = (const float*)d_in[1];
    const float* b_fioux = (const float*)d_in[2];
    const float* Wiouh   = (const float*)d_in[3];
    const float* Wfh     = (const float*)d_in[4];
    const int*   left_idx  = (const int*)d_in[5];
    const int*   right_idx = (const int*)d_in[6];

    half_t* C   = (half_t*)d_ws;                              // [1023][128][300] fp16
    short*  H   = (short*)(C + (size_t)NODES * BATCH * MEM);  // [1023][128][320] bf16
    short* WpkN = H + (size_t)NODES * BATCH * NP;             // 2000 frag-blocks
    short* WpkL = WpkN + (size_t)2000 * 512;                  // 600 frag-blocks
    short* X    = WpkL + (size_t)600 * 512;                   // [512][128][320] bf16
    float* out  = (float*)d_out;

    pack_x<<<(LEAVES * BATCH * (NP / 4) + 255) / 256, 256, 0, stream>>>(inputs, X);
    pack_leaf_w<<<150, 256, 0, stream>>>(Wfioux, WpkL);
    pack_node_w<<<500, 256, 0, stream>>>(Wiouh, Wfh, WpkN);

    leaf_mfma<<<dim3(LEAVES, 5), 256, 0, stream>>>(X, WpkL, b_fioux, C, H);

    static const int starts[9] = {512, 768, 896, 960, 992, 1008, 1016, 1020, 1022};
    static const int sizes [9] = {256, 128,  64,  32,  16,    8,    4,    2,    1};
    for (int lvl = 0; lvl < 9; ++lvl) {
        bool root = (lvl == 8);
        node_mfma<<<dim3(sizes[lvl], 10), 256, 0, stream>>>(
            WpkN, b_fioux, left_idx, right_idx, C, H, starts[lvl],
            root ? out : nullptr);
    }
}